// Round 1
// baseline (94.313 us; speedup 1.0000x reference)
//
#include <hip/hip_runtime.h>
#include <math.h>

#define UNITS 4096
#define BLK 256

__device__ __forceinline__ float wave_sum64(float v) {
#pragma unroll
  for (int o = 32; o > 0; o >>= 1) v += __shfl_down(v, o, 64);
  return v;
}

// Block-wide sum for 4 waves. Leading barrier protects WAR reuse of `part`.
__device__ __forceinline__ float block_sum(float v, float* part) {
  const int tid = threadIdx.x;
  __syncthreads();
  v = wave_sum64(v);
  if ((tid & 63) == 0) part[tid >> 6] = v;
  __syncthreads();
  return part[0] + part[1] + part[2] + part[3];
}

__global__ __launch_bounds__(BLK) void srp_kernel(
    const float* __restrict__ pw, const float* __restrict__ bs,
    const float* __restrict__ msk, const float* __restrict__ budget,
    const float* __restrict__ prev, const int* __restrict__ cf,
    float* __restrict__ out) {
  constexpr float TOPK_RATIO = 0.35f;
  constexpr float MIN_BW = 0.1f;
  constexpr float BIAS_W = 0.15f;
  constexpr float TEMP = 0.12f;
  constexpr float EPSF = 1e-6f;
  constexpr float HIV = 1.25f;  // scores < 1 + 0.15*1.1 = 1.165

  __shared__ float s_sc[UNITS];   // 16 KB: scores, later prev-stash / gated sel
  __shared__ int s_h1[256];
  __shared__ int s_h2[256];
  __shared__ float s_part[4];
  __shared__ int s_b1, s_rem, s_b2;

  const int tid = threadIdx.x;
  const int row = blockIdx.x;
  const size_t base = (size_t)row * UNITS;

  s_h1[tid] = 0;
  s_h2[tid] = 0;

  const float4* pw4 = reinterpret_cast<const float4*>(pw + base);
  const float4* bs4 = reinterpret_cast<const float4*>(bs + base);
  const float4* mk4 = reinterpret_cast<const float4*>(msk + base);

  __syncthreads();  // histograms zeroed

  const float binscale1 = 256.0f / HIV;
  float visl = 0.0f;
  // Load + score + level-1 histogram. mask is a prefix-of-ones, so m.x==0
  // implies the whole 4-chunk is invalid -> skip pw/bs loads entirely.
  for (int i = tid; i < UNITS / 4; i += BLK) {
    float4 m = mk4[i];
    visl += m.x + m.y + m.z + m.w;
    if (m.x > 0.0f) {
      float4 w = pw4[i];
      float4 b = bs4[i];
      float4 sc;
      sc.x = (fmaxf(w.x, 0.f) + BIAS_W * (MIN_BW + fmaxf(b.x, 0.f))) * m.x;
      sc.y = (fmaxf(w.y, 0.f) + BIAS_W * (MIN_BW + fmaxf(b.y, 0.f))) * m.y;
      sc.z = (fmaxf(w.z, 0.f) + BIAS_W * (MIN_BW + fmaxf(b.z, 0.f))) * m.z;
      sc.w = (fmaxf(w.w, 0.f) + BIAS_W * (MIN_BW + fmaxf(b.w, 0.f))) * m.w;
      reinterpret_cast<float4*>(s_sc)[i] = sc;
      atomicAdd(&s_h1[min(255, (int)(sc.x * binscale1))], 1);
      if (m.y > 0.f) atomicAdd(&s_h1[min(255, (int)(sc.y * binscale1))], 1);
      if (m.z > 0.f) atomicAdd(&s_h1[min(255, (int)(sc.z * binscale1))], 1);
      if (m.w > 0.f) atomicAdd(&s_h1[min(255, (int)(sc.w * binscale1))], 1);
    }
  }

  float visible = block_sum(visl, s_part);  // exact: integer-valued sum
  int L = (int)(visible + 0.5f);

  float kf = fmaxf(1.0f, rintf(visible * TOPK_RATIO));  // rintf = round-half-even = jnp.round
  kf = fminf(kf, fmaxf(visible, 1.0f));
  int kk = (int)kf;
  bool no_gate = (kf >= visible);  // block-uniform

  float thr = 0.0f;
  if (!no_gate) {
    // level-1 scan (descending) to find bucket of the kk-th largest
    if (tid == 0) {
      int cum = 0, b1 = 0, rem = kk;
      bool found = false;
      for (int b = 255; b >= 0; --b) {
        int h = s_h1[b];
        int nc = cum + h;
        if (!found && nc >= kk) { b1 = b; rem = kk - cum; found = true; }
        cum = nc;
      }
      s_b1 = b1;
      s_rem = rem;
    }
    __syncthreads();
    const int b1 = s_b1;
    const int rem = s_rem;
    const float lo1 = (float)b1 * (HIV / 256.0f);
    const float binscale2 = (256.0f * 256.0f) / HIV;
    for (int c = tid; c < L; c += BLK) {
      float s = s_sc[c];
      int bb = min(255, (int)(s * binscale1));  // identical formula -> consistent binning
      if (bb == b1) {
        int b2 = (int)((s - lo1) * binscale2);
        b2 = max(0, min(255, b2));
        atomicAdd(&s_h2[b2], 1);
      }
    }
    __syncthreads();
    if (tid == 0) {
      int cum = 0, b2v = 0;
      bool found = false;
      for (int b = 255; b >= 0; --b) {
        int h = s_h2[b];
        int nc = cum + h;
        if (!found && nc >= rem) { b2v = b; found = true; }
        cum = nc;
      }
      s_b2 = b2v;
    }
    __syncthreads();
    // thr within 1.9e-5 of the exact kk-th largest; sigmoid(TEMP=0.12) + output
    // normalization make this far below the absmax threshold.
    thr = (float)b1 * (HIV / 256.0f) + (float)s_b2 * (HIV / (256.0f * 256.0f));
  }

  // ---- prefix-reuse budget allocation ----
  int vf = cf[row];
  vf = min(max(vf, 0), UNITS);
  int pvf = min(vf, L);

  float psl = 0.0f;
  for (int c = tid; c < pvf; c += BLK) {
    float p = prev[base + c];
    psl += p;
    s_sc[c] = p;  // stash for the write phase (select is done with s_sc[<pvf])
  }
  float prefix_sum = block_sum(psl, s_part);

  const float inv_temp = 1.0f / TEMP;
  float tsl = 0.0f;
  for (int c = pvf + tid; c < L; c += BLK) {
    float s = s_sc[c];
    float sel = s;
    if (!no_gate) {
      float g = 1.0f / (1.0f + expf(-(s - thr) * inv_temp));
      sel = s * g;
    }
    s_sc[c] = sel;  // gated candidate, reused in write phase
    tsl += sel;
  }
  float tail_cand = block_sum(tsl, s_part);

  const int tc = L - pvf;
  float cand_sum = tail_cand + (tc > 0 ? EPSF : 0.0f);
  float remaining = fmaxf(budget[row] - prefix_sum, 0.0f);
  float total = fmaxf(cand_sum, EPSF);
  float scale = remaining / total;
  float fb = (tc > 0) ? (EPSF / (float)tc) : 0.0f;

  __syncthreads();  // all s_sc writes visible before cross-thread reads

  float4* out4 = reinterpret_cast<float4*>(out + base);
  for (int i = tid; i < UNITS / 4; i += BLK) {
    int c0 = i * 4;
    float v0, v1, v2, v3;
    {
      int c = c0 + 0;
      v0 = (c < pvf) ? s_sc[c] : (c < L) ? (s_sc[c] + fb) * scale : 0.0f;
    }
    {
      int c = c0 + 1;
      v1 = (c < pvf) ? s_sc[c] : (c < L) ? (s_sc[c] + fb) * scale : 0.0f;
    }
    {
      int c = c0 + 2;
      v2 = (c < pvf) ? s_sc[c] : (c < L) ? (s_sc[c] + fb) * scale : 0.0f;
    }
    {
      int c = c0 + 3;
      v3 = (c < pvf) ? s_sc[c] : (c < L) ? (s_sc[c] + fb) * scale : 0.0f;
    }
    float4 o;
    o.x = v0; o.y = v1; o.z = v2; o.w = v3;
    out4[i] = o;
  }
}

extern "C" void kernel_launch(void* const* d_in, const int* in_sizes, int n_in,
                              void* d_out, int out_size, void* d_ws, size_t ws_size,
                              hipStream_t stream) {
  const float* pw = (const float*)d_in[0];
  const float* bs = (const float*)d_in[1];
  const float* msk = (const float*)d_in[2];
  const float* bud = (const float*)d_in[3];
  const float* prev = (const float*)d_in[4];
  const int* cf = (const int*)d_in[5];
  float* out = (float*)d_out;
  const int rows = out_size / UNITS;
  srp_kernel<<<dim3(rows), dim3(BLK), 0, stream>>>(pw, bs, msk, bud, prev, cf, out);
}

// Round 2
// 36.419 us; speedup vs baseline: 2.5897x; 2.5897x over previous
//
#include <hip/hip_runtime.h>
#include <math.h>

#define UNITS 4096
#define BLK 256

// Parallel "find k-th largest bucket": inclusive suffix-scan of a 256-bin
// histogram (thread tid owns bin 255-tid), then the unique crossing thread
// publishes {bin, remainder}. Caller must barrier AFTER hist writes, BEFORE
// calling. Contains 2 internal barriers.
__device__ __forceinline__ int2 suffix_select(const int* __restrict__ hist,
                                              int target, int tid,
                                              int* s_w, int* s_binrem) {
  const int v = hist[255 - tid];
  const int lane = tid & 63;
  const int wid = tid >> 6;
  int x = v;
#pragma unroll
  for (int o = 1; o < 64; o <<= 1) {
    int y = __shfl_up(x, o, 64);
    if (lane >= o) x += y;
  }
  if (lane == 63) s_w[wid] = x;
  __syncthreads();
  if (wid > 0) x += s_w[0];
  if (wid > 1) x += s_w[1];
  if (wid > 2) x += s_w[2];
  // x = S(b) = count of elements >= lower edge of bin b; S increasing in tid.
  // Unique crossing: S(b) >= target while S(b+1) = x - v < target.
  if (x >= target && (x - v) < target) {
    s_binrem[0] = 255 - tid;
    s_binrem[1] = target - (x - v);
  }
  __syncthreads();
  return make_int2(s_binrem[0], s_binrem[1]);
}

__global__ __launch_bounds__(BLK) void srp_kernel(
    const float* __restrict__ pw, const float* __restrict__ bs,
    const float* __restrict__ msk, const float* __restrict__ budget,
    const float* __restrict__ prev, const int* __restrict__ cf,
    float* __restrict__ out) {
  constexpr float TOPK_RATIO = 0.35f;
  constexpr float MIN_BW = 0.1f;
  constexpr float BIAS_W = 0.15f;
  constexpr float TEMP = 0.12f;
  constexpr float EPSF = 1e-6f;
  constexpr float HIV = 1.25f;  // scores < 1 + 0.15*1.1 = 1.165
  const float binscale1 = 256.0f / HIV;
  const float binscale2 = 65536.0f / HIV;

  __shared__ int s_h1[256];
  __shared__ int s_h2[256];
  __shared__ int s_w[4];
  __shared__ int s_binrem[2];
  __shared__ float s_part[8];
  __shared__ int s_L;

  const int tid = threadIdx.x;
  const int row = blockIdx.x;
  const size_t base = (size_t)row * UNITS;

  s_h1[tid] = 0;
  s_h2[tid] = 0;

  // ---- find L = prefix length of the ones-mask: 3-round ballot probe ----
  // mask[i] == 1  <=>  i < L, L in [1, 4096]. ~18 cache lines instead of 16KB.
  if (tid < 64) {
    bool t1 = false;
    if (tid < 8) t1 = msk[base + tid * 512 + 511] > 0.0f;
    const int q1 = __popcll(__ballot(t1));  // L in [q1*512, q1*512+512)
    int Lv;
    if (q1 == 8) {
      Lv = 4096;
    } else {
      bool t2 = false;
      if (tid < 8) t2 = msk[base + q1 * 512 + tid * 64 + 63] > 0.0f;
      const int q2 = __popcll(__ballot(t2));  // L in [q0, q0+64)
      const int q0 = q1 * 512 + q2 * 64;
      const bool t3 = msk[base + q0 + tid] > 0.0f;
      Lv = q0 + __popcll(__ballot(t3));
    }
    if (tid == 0) s_L = Lv;
  }
  __syncthreads();  // also covers histogram zeroing

  const int L = s_L;
  const float Lf = (float)L;
  float kf = fmaxf(1.0f, rintf(Lf * TOPK_RATIO));  // rintf == jnp.round (half-even)
  kf = fminf(kf, fmaxf(Lf, 1.0f));
  const int kk = (int)kf;
  const bool no_gate = (kf >= Lf);  // block-uniform

  int vf = cf[row];
  vf = min(max(vf, 0), UNITS);
  const int vfL = min(vf, L);  // prefix region [0, vfL): out = prev

  const float4* pw4 = reinterpret_cast<const float4*>(pw + base);
  const float4* bs4 = reinterpret_cast<const float4*>(bs + base);
  const float4* pv4 = reinterpret_cast<const float4*>(prev + base);

  // ---- pass 1: scores + prev into registers, level-1 histogram ----
  float4 sc[4];
  float4 pv[4];
  float prefl = 0.0f;
#pragma unroll
  for (int j = 0; j < 4; ++j) {
    const int i = tid + j * BLK;
    const int c0 = i * 4;
    float4 s = make_float4(0.f, 0.f, 0.f, 0.f);
    float4 p = make_float4(0.f, 0.f, 0.f, 0.f);
    if (c0 < L) {
      const float4 w = pw4[i];
      const float4 b = bs4[i];
      s.x = fmaxf(w.x, 0.f) + BIAS_W * (MIN_BW + fmaxf(b.x, 0.f));
      s.y = (c0 + 1 < L) ? fmaxf(w.y, 0.f) + BIAS_W * (MIN_BW + fmaxf(b.y, 0.f)) : 0.f;
      s.z = (c0 + 2 < L) ? fmaxf(w.z, 0.f) + BIAS_W * (MIN_BW + fmaxf(b.z, 0.f)) : 0.f;
      s.w = (c0 + 3 < L) ? fmaxf(w.w, 0.f) + BIAS_W * (MIN_BW + fmaxf(b.w, 0.f)) : 0.f;
      atomicAdd(&s_h1[min(255, (int)(s.x * binscale1))], 1);
      if (c0 + 1 < L) atomicAdd(&s_h1[min(255, (int)(s.y * binscale1))], 1);
      if (c0 + 2 < L) atomicAdd(&s_h1[min(255, (int)(s.z * binscale1))], 1);
      if (c0 + 3 < L) atomicAdd(&s_h1[min(255, (int)(s.w * binscale1))], 1);
    }
    if (c0 < vfL) {
      const float4 t = pv4[i];
      p.x = t.x;
      p.y = (c0 + 1 < vfL) ? t.y : 0.f;
      p.z = (c0 + 2 < vfL) ? t.z : 0.f;
      p.w = (c0 + 3 < vfL) ? t.w : 0.f;
      prefl += p.x + p.y + p.z + p.w;
    }
    sc[j] = s;
    pv[j] = p;
  }

  // ---- threshold via two-level 256-bin select (parallel scans) ----
  float thr = 0.0f;
  if (!no_gate) {
    __syncthreads();  // s_h1 complete
    const int2 br1 = suffix_select(s_h1, kk, tid, s_w, s_binrem);
    const int b1 = br1.x;
    const int rem = br1.y;
    const float lo1 = (float)b1 * (HIV / 256.0f);
    // level-2 histogram straight from registers
#pragma unroll
    for (int j = 0; j < 4; ++j) {
      const int c0 = (tid + j * BLK) * 4;
      if (c0 < L) {
        const float4 s = sc[j];
        {
          const int bb = min(255, (int)(s.x * binscale1));
          if (bb == b1)
            atomicAdd(&s_h2[max(0, min(255, (int)((s.x - lo1) * binscale2)))], 1);
        }
        if (c0 + 1 < L) {
          const int bb = min(255, (int)(s.y * binscale1));
          if (bb == b1)
            atomicAdd(&s_h2[max(0, min(255, (int)((s.y - lo1) * binscale2)))], 1);
        }
        if (c0 + 2 < L) {
          const int bb = min(255, (int)(s.z * binscale1));
          if (bb == b1)
            atomicAdd(&s_h2[max(0, min(255, (int)((s.z - lo1) * binscale2)))], 1);
        }
        if (c0 + 3 < L) {
          const int bb = min(255, (int)(s.w * binscale1));
          if (bb == b1)
            atomicAdd(&s_h2[max(0, min(255, (int)((s.w - lo1) * binscale2)))], 1);
        }
      }
    }
    __syncthreads();  // s_h2 complete
    const int2 br2 = suffix_select(s_h2, rem, tid, s_w, s_binrem);
    // thr within HIV/65536 = 1.9e-5 of the exact kk-th largest; after the
    // TEMP=0.12 sigmoid + output renormalization this is far below tolerance.
    thr = lo1 + (float)br2.x * (HIV / 65536.0f);
  }

  // ---- gating + tail sum, all in registers ----
  const float inv_temp = 1.0f / TEMP;
  float tsl = 0.0f;
#pragma unroll
  for (int j = 0; j < 4; ++j) {
    const int c0 = (tid + j * BLK) * 4;
    float4 s = sc[j];
    float4 sel;
    if (no_gate) {
      sel = s;
    } else {
      sel.x = s.x / (1.0f + __expf((thr - s.x) * inv_temp));
      sel.y = s.y / (1.0f + __expf((thr - s.y) * inv_temp));
      sel.z = s.z / (1.0f + __expf((thr - s.z) * inv_temp));
      sel.w = s.w / (1.0f + __expf((thr - s.w) * inv_temp));
    }
    tsl += ((c0 >= vfL && c0 < L) ? sel.x : 0.f) +
           ((c0 + 1 >= vfL && c0 + 1 < L) ? sel.y : 0.f) +
           ((c0 + 2 >= vfL && c0 + 2 < L) ? sel.z : 0.f) +
           ((c0 + 3 >= vfL && c0 + 3 < L) ? sel.w : 0.f);
    sc[j] = sel;
  }

  // ---- combined block reduction of (prefix_sum, tail_cand) ----
  {
    float a = prefl;
    float b = tsl;
#pragma unroll
    for (int o = 32; o > 0; o >>= 1) {
      a += __shfl_down(a, o, 64);
      b += __shfl_down(b, o, 64);
    }
    if ((tid & 63) == 0) {
      s_part[tid >> 6] = a;
      s_part[4 + (tid >> 6)] = b;
    }
  }
  __syncthreads();
  const float prefix_sum = s_part[0] + s_part[1] + s_part[2] + s_part[3];
  const float tail_cand = s_part[4] + s_part[5] + s_part[6] + s_part[7];

  const int tc = L - vfL;
  const float cand_sum = tail_cand + (tc > 0 ? EPSF : 0.0f);
  const float remaining = fmaxf(budget[row] - prefix_sum, 0.0f);
  const float total = fmaxf(cand_sum, EPSF);
  const float scale = remaining / total;
  const float fb = (tc > 0) ? (EPSF / (float)tc) : 0.0f;

  // ---- write, all from registers ----
  float4* out4 = reinterpret_cast<float4*>(out + base);
#pragma unroll
  for (int j = 0; j < 4; ++j) {
    const int i = tid + j * BLK;
    const int c0 = i * 4;
    const float4 s = sc[j];
    const float4 p = pv[j];
    float4 o;
    o.x = (c0 < vfL) ? p.x : ((c0 < L) ? (s.x + fb) * scale : 0.f);
    o.y = (c0 + 1 < vfL) ? p.y : ((c0 + 1 < L) ? (s.y + fb) * scale : 0.f);
    o.z = (c0 + 2 < vfL) ? p.z : ((c0 + 2 < L) ? (s.z + fb) * scale : 0.f);
    o.w = (c0 + 3 < vfL) ? p.w : ((c0 + 3 < L) ? (s.w + fb) * scale : 0.f);
    out4[i] = o;
  }
}

extern "C" void kernel_launch(void* const* d_in, const int* in_sizes, int n_in,
                              void* d_out, int out_size, void* d_ws, size_t ws_size,
                              hipStream_t stream) {
  const float* pw = (const float*)d_in[0];
  const float* bs = (const float*)d_in[1];
  const float* msk = (const float*)d_in[2];
  const float* bud = (const float*)d_in[3];
  const float* prev = (const float*)d_in[4];
  const int* cf = (const int*)d_in[5];
  float* out = (float*)d_out;
  const int rows = out_size / UNITS;
  srp_kernel<<<dim3(rows), dim3(BLK), 0, stream>>>(pw, bs, msk, bud, prev, cf, out);
}

// Round 3
// 31.757 us; speedup vs baseline: 2.9698x; 1.1468x over previous
//
#include <hip/hip_runtime.h>
#include <math.h>

#define UNITS 4096
#define BLK 256
#define NBINS 1024

__global__ __launch_bounds__(BLK) void srp_kernel(
    const float* __restrict__ pw, const float* __restrict__ bs,
    const float* __restrict__ msk, const float* __restrict__ budget,
    const float* __restrict__ prev, const int* __restrict__ cf,
    float* __restrict__ out) {
  constexpr float TOPK_RATIO = 0.35f;
  constexpr float MIN_BW = 0.1f;
  constexpr float BIAS_W = 0.15f;
  constexpr float TEMP = 0.12f;
  constexpr float EPSF = 1e-6f;
  constexpr float HIV = 1.25f;  // scores <= 1 + 0.15*1.1 = 1.165 < 1.25
  const float binscale = (float)NBINS / HIV;

  __shared__ int s_h[NBINS];   // 4 KB single-level histogram
  __shared__ int s_w[4];
  __shared__ int s_bin;
  __shared__ float s_part[8];
  __shared__ int s_L;

  const int tid = threadIdx.x;
  const int row = blockIdx.x;
  const size_t base = (size_t)row * UNITS;

  reinterpret_cast<int4*>(s_h)[tid] = make_int4(0, 0, 0, 0);

  // ---- L = prefix length of the ones-mask: 3-round ballot probe ----
  if (tid < 64) {
    bool t1 = false;
    if (tid < 8) t1 = msk[base + tid * 512 + 511] > 0.0f;
    const int q1 = __popcll(__ballot(t1));  // L in [q1*512, q1*512+512)
    int Lv;
    if (q1 == 8) {
      Lv = 4096;
    } else {
      bool t2 = false;
      if (tid < 8) t2 = msk[base + q1 * 512 + tid * 64 + 63] > 0.0f;
      const int q2 = __popcll(__ballot(t2));
      const int q0 = q1 * 512 + q2 * 64;
      const bool t3 = msk[base + q0 + tid] > 0.0f;
      Lv = q0 + __popcll(__ballot(t3));
    }
    if (tid == 0) s_L = Lv;
  }
  __syncthreads();  // covers histogram zeroing + s_L

  const int L = s_L;
  const float Lf = (float)L;
  float kf = fmaxf(1.0f, rintf(Lf * TOPK_RATIO));  // rintf == jnp.round (half-even)
  kf = fminf(kf, fmaxf(Lf, 1.0f));
  const int kk = (int)kf;
  const bool no_gate = (kf >= Lf);  // block-uniform

  int vf = cf[row];
  vf = min(max(vf, 0), UNITS);
  const int vfL = min(vf, L);  // prefix region [0, vfL): out = prev

  const float4* pw4 = reinterpret_cast<const float4*>(pw + base);
  const float4* bs4 = reinterpret_cast<const float4*>(bs + base);
  const float4* pv4 = reinterpret_cast<const float4*>(prev + base);

  // ---- pass 1: scores + prev into registers, histogram ----
  float4 sc[4];
  float4 pv[4];
  float prefl = 0.0f;
#pragma unroll
  for (int j = 0; j < 4; ++j) {
    const int i = tid + j * BLK;
    const int c0 = i * 4;
    float4 s = make_float4(0.f, 0.f, 0.f, 0.f);
    float4 p = make_float4(0.f, 0.f, 0.f, 0.f);
    if (c0 < L) {
      const float4 w = pw4[i];
      const float4 b = bs4[i];
      s.x = fmaxf(w.x, 0.f) + BIAS_W * (MIN_BW + fmaxf(b.x, 0.f));
      s.y = fmaxf(w.y, 0.f) + BIAS_W * (MIN_BW + fmaxf(b.y, 0.f));
      s.z = fmaxf(w.z, 0.f) + BIAS_W * (MIN_BW + fmaxf(b.z, 0.f));
      s.w = fmaxf(w.w, 0.f) + BIAS_W * (MIN_BW + fmaxf(b.w, 0.f));
      if (c0 + 3 < L) {
        atomicAdd(&s_h[min(NBINS - 1, (int)(s.x * binscale))], 1);
        atomicAdd(&s_h[min(NBINS - 1, (int)(s.y * binscale))], 1);
        atomicAdd(&s_h[min(NBINS - 1, (int)(s.z * binscale))], 1);
        atomicAdd(&s_h[min(NBINS - 1, (int)(s.w * binscale))], 1);
      } else {
        if (c0 + 1 >= L) s.y = 0.f;
        if (c0 + 2 >= L) s.z = 0.f;
        if (c0 + 3 >= L) s.w = 0.f;
        atomicAdd(&s_h[min(NBINS - 1, (int)(s.x * binscale))], 1);
        if (c0 + 1 < L) atomicAdd(&s_h[min(NBINS - 1, (int)(s.y * binscale))], 1);
        if (c0 + 2 < L) atomicAdd(&s_h[min(NBINS - 1, (int)(s.z * binscale))], 1);
        if (c0 + 3 < L) atomicAdd(&s_h[min(NBINS - 1, (int)(s.w * binscale))], 1);
      }
    }
    if (c0 < vfL) {
      const float4 t = pv4[i];
      p.x = t.x;
      p.y = (c0 + 1 < vfL) ? t.y : 0.f;
      p.z = (c0 + 2 < vfL) ? t.z : 0.f;
      p.w = (c0 + 3 < vfL) ? t.w : 0.f;
      prefl += p.x + p.y + p.z + p.w;
    }
    sc[j] = s;
    pv[j] = p;
  }

  // ---- single-level 1024-bin select: thr = lower edge of bin holding the
  // kk-th largest. err <= HIV/1024 = 1.22e-3; sigmoid(T=0.12) + output
  // renormalization damp this far below the absmax tolerance. ----
  float thr = 0.0f;
  if (!no_gate) {
    __syncthreads();  // s_h complete
    // thread tid owns bin-group g=255-tid (4 consecutive bins, high->low tid)
    const int g = 255 - tid;
    const int4 hv = reinterpret_cast<const int4*>(s_h)[g];
    const int v = hv.x + hv.y + hv.z + hv.w;
    const int lane = tid & 63;
    const int wid = tid >> 6;
    int x = v;
#pragma unroll
    for (int o = 1; o < 64; o <<= 1) {
      int y = __shfl_up(x, o, 64);
      if (lane >= o) x += y;
    }
    if (lane == 63) s_w[wid] = x;
    __syncthreads();
    if (wid > 0) x += s_w[0];
    if (wid > 1) x += s_w[1];
    if (wid > 2) x += s_w[2];
    // x = count of elements in bins >= 4g. Unique crossing thread:
    if (x >= kk && (x - v) < kk) {
      int cum = x - v;  // count strictly above this group
      int bin;
      cum += hv.w;
      if (cum >= kk) bin = g * 4 + 3;
      else {
        cum += hv.z;
        if (cum >= kk) bin = g * 4 + 2;
        else {
          cum += hv.y;
          bin = (cum >= kk) ? g * 4 + 1 : g * 4;
        }
      }
      s_bin = bin;
    }
    __syncthreads();
    thr = (float)s_bin * (HIV / (float)NBINS);
  }

  // ---- gating + tail sum (tail region only), in registers ----
  const float inv_temp = 1.0f / TEMP;
  float tsl = 0.0f;
#pragma unroll
  for (int j = 0; j < 4; ++j) {
    const int c0 = (tid + j * BLK) * 4;
    if (c0 + 3 >= vfL && c0 < L) {   // chunk intersects tail region [vfL, L)
      float4 s = sc[j];
      float4 sel;
      if (no_gate) {
        sel = s;
      } else {
        sel.x = s.x * __builtin_amdgcn_rcpf(1.0f + __expf((thr - s.x) * inv_temp));
        sel.y = s.y * __builtin_amdgcn_rcpf(1.0f + __expf((thr - s.y) * inv_temp));
        sel.z = s.z * __builtin_amdgcn_rcpf(1.0f + __expf((thr - s.z) * inv_temp));
        sel.w = s.w * __builtin_amdgcn_rcpf(1.0f + __expf((thr - s.w) * inv_temp));
      }
      tsl += ((c0 >= vfL && c0 < L) ? sel.x : 0.f) +
             ((c0 + 1 >= vfL && c0 + 1 < L) ? sel.y : 0.f) +
             ((c0 + 2 >= vfL && c0 + 2 < L) ? sel.z : 0.f) +
             ((c0 + 3 >= vfL && c0 + 3 < L) ? sel.w : 0.f);
      sc[j] = sel;
    }
  }

  // ---- combined block reduction of (prefix_sum, tail_cand) ----
  {
    float a = prefl;
    float b = tsl;
#pragma unroll
    for (int o = 32; o > 0; o >>= 1) {
      a += __shfl_down(a, o, 64);
      b += __shfl_down(b, o, 64);
    }
    if ((tid & 63) == 0) {
      s_part[tid >> 6] = a;
      s_part[4 + (tid >> 6)] = b;
    }
  }
  __syncthreads();
  const float prefix_sum = s_part[0] + s_part[1] + s_part[2] + s_part[3];
  const float tail_cand = s_part[4] + s_part[5] + s_part[6] + s_part[7];

  const int tc = L - vfL;
  const float cand_sum = tail_cand + (tc > 0 ? EPSF : 0.0f);
  const float remaining = fmaxf(budget[row] - prefix_sum, 0.0f);
  const float total = fmaxf(cand_sum, EPSF);
  const float scale = remaining / total;
  const float fb = (tc > 0) ? (EPSF / (float)tc) : 0.0f;

  // ---- write, wave-uniform fast paths (boundaries hit <=2 waves/row) ----
  float4* out4 = reinterpret_cast<float4*>(out + base);
#pragma unroll
  for (int j = 0; j < 4; ++j) {
    const int i = tid + j * BLK;
    const int c0 = i * 4;
    const float4 s = sc[j];
    const float4 p = pv[j];
    float4 o;
    if (c0 + 3 < vfL) {
      o = p;                                 // pure prefix chunk
    } else if (c0 >= L) {
      o = make_float4(0.f, 0.f, 0.f, 0.f);   // pure invalid chunk
    } else if (c0 >= vfL && c0 + 3 < L) {
      o.x = (s.x + fb) * scale;              // pure tail chunk
      o.y = (s.y + fb) * scale;
      o.z = (s.z + fb) * scale;
      o.w = (s.w + fb) * scale;
    } else {                                  // boundary chunk, per-component
      o.x = (c0 < vfL) ? p.x : ((c0 < L) ? (s.x + fb) * scale : 0.f);
      o.y = (c0 + 1 < vfL) ? p.y : ((c0 + 1 < L) ? (s.y + fb) * scale : 0.f);
      o.z = (c0 + 2 < vfL) ? p.z : ((c0 + 2 < L) ? (s.z + fb) * scale : 0.f);
      o.w = (c0 + 3 < vfL) ? p.w : ((c0 + 3 < L) ? (s.w + fb) * scale : 0.f);
    }
    out4[i] = o;
  }
}

extern "C" void kernel_launch(void* const* d_in, const int* in_sizes, int n_in,
                              void* d_out, int out_size, void* d_ws, size_t ws_size,
                              hipStream_t stream) {
  const float* pw = (const float*)d_in[0];
  const float* bs = (const float*)d_in[1];
  const float* msk = (const float*)d_in[2];
  const float* bud = (const float*)d_in[3];
  const float* prev = (const float*)d_in[4];
  const int* cf = (const int*)d_in[5];
  float* out = (float*)d_out;
  const int rows = out_size / UNITS;
  srp_kernel<<<dim3(rows), dim3(BLK), 0, stream>>>(pw, bs, msk, bud, prev, cf, out);
}